// Round 20
// baseline (121.646 us; speedup 1.0000x reference)
//
#include <hip/hip_runtime.h>
#include <stdint.h>

#define B_ 8
#define C_ 256
#define H_ 96
#define W_ 160
#define ND 9
#define NDISP 81
#define NCHUNK 64              // chunks of 4 channels (2 f16-pair sets)
#define TX 4
#define NXG 20                 // x-groups per half (80 = 20*4)
#define NTHR 256               // 4 waves
#define NCOMP 180              // 9 dy * 20 xg
// Per-buffer: two pair-layouts at p*PAIR_B. Pair layout (bytes):
//   in1: 80 words @0 (320 B); in2 row r: 88 words @ 320 + r*352.
#define IN2_OFF 320
#define ROW_B 352              // 22*16
#define PAIR_B 3520            // 3488 padded to 16-mult
#define BUF_B 7040             // 2 pairs
#define NBUF 3                 // ring-3, write-ahead-1 -> 64 barriers total
#define NSEG 218               // uint4 segments per pair
#define HW (H_ * W_)
#define CHSTEP (4 * HW)        // 4 channels per chunk

typedef __attribute__((ext_vector_type(2))) _Float16 half2v;

__device__ __forceinline__ unsigned pk(float lo, float hi) {
    return __builtin_bit_cast(unsigned, __builtin_amdgcn_cvt_pkrtz(lo, hi));
}
__device__ __forceinline__ float dot2acc(unsigned a, unsigned w, float acc) {
#if __has_builtin(__builtin_amdgcn_fdot2)
    return __builtin_amdgcn_fdot2(__builtin_bit_cast(half2v, a),
                                  __builtin_bit_cast(half2v, w), acc, false);
#else
    half2v av = __builtin_bit_cast(half2v, a);
    half2v wv = __builtin_bit_cast(half2v, w);
    return acc + (float)av.x * (float)wv.x + (float)av.y * (float)wv.y;
#endif
}

// uint4 segment s (within a pair) -> fp32 source (even-channel base) + LDS
// byte offset (pair-local). Clamped cells = finite garbage, masked later.
__device__ __forceinline__ const float* seg_src(int s, int b, int y, int h,
        const float* in1, const float* in2, int* woff)
{
    if (s < 20) {                          // in1: x = 80h + 4s (all real)
        *woff = s * 16;
        return in1 + ((size_t)(b * C_) * H_ + y) * W_ + 80 * h + 4 * s;
    }
    const int t = s - 20;
    const int r = t / 22, k = t - r * 22;  // dy row, word-seg
    *woff = IN2_OFF + r * ROW_B + k * 16;
    int row = y + r - 4;
    row = row < 0 ? 0 : (row >= H_ ? H_ - 1 : row);      // clamp; masked later
    int x = 80 * h - 4 + 4 * k;
    x = x < 0 ? 0 : (x > W_ - 4 ? W_ - 4 : x);           // clamp; masked later
    return in2 + ((size_t)(b * C_) * H_ + row) * W_ + x; // 16B-aligned
}

__global__ __launch_bounds__(NTHR) void corr_ck4_kernel(
    const float* __restrict__ in1,
    const float* __restrict__ in2,
    float* __restrict__ out)
{
    __shared__ __align__(16) unsigned lds[NBUF * BUF_B / 4];   // 21120 B

    const int tid = threadIdx.x;
    const int b   = blockIdx.x & 7;       // XCD swizzle: batch pinned to XCD
    const int idx = blockIdx.x >> 3;      // 0..191
    const int y   = idx >> 1;
    const int h   = idx & 1;              // x half

    // ---- staging: thread t stages seg t of BOTH pairs (pair1 = src + 2HW,
    // dst + PAIR_B); invalid for tid >= 218
    int w0off = 0;
    const bool v0 = tid < NSEG;
    const float* p0 = in1;                // safe dummy (stays in-bounds)
    if (v0) p0 = seg_src(tid, b, y, h, in1, in2, &w0off);

    // ---- compute coords (lanes 0..179): dy-major
    const bool isComp = (tid < NCOMP);
    const int  dy = isComp ? (tid / NXG) : 0;
    const int  xg = isComp ? (tid % NXG) : 0;
    const int  x0 = 80 * h + TX * xg;
    const bool rowOk = (y + dy - 4 >= 0) && (y + dy - 4 < H_);
    const bool mzW0 = (h == 0) && (xg == 0);        // words x [-4,0)
    const bool mzW2 = (h == 1) && (xg == NXG - 1);  // words x [160,164)

    const int aof = 16 * xg;                         // in1 words [4xg, 4xg+4)
    const int wof = IN2_OFF + dy * ROW_B + 16 * xg;  // in2 words [4xg-4,4xg+8)

    float acc[ND][TX];
    #pragma unroll
    for (int dx = 0; dx < ND; ++dx)
        #pragma unroll
        for (int j = 0; j < TX; ++j) acc[dx][j] = 0.f;

    // single staging set (consumed at body start by CVTW, reloaded after)
    float4 SAp0, SAp1, SAq0, SAq1;

    #define LOADS do {                                                        \
        SAp0 = *(const float4*)(p0);           /* pair0 ch-lo  */             \
        SAp1 = *(const float4*)(p0 + HW);      /* pair0 ch-hi  */             \
        SAq0 = *(const float4*)(p0 + 2 * HW);  /* pair1 ch-lo  */             \
        SAq1 = *(const float4*)(p0 + 3 * HW);  /* pair1 ch-hi  */             \
        p0 += CHSTEP;                                                         \
    } while (0);

    #define CVTW(BUFI) do {                                                   \
        if (v0) {                                                             \
            char* base = (char*)lds + (BUFI) * BUF_B + w0off;                 \
            *(uint4*)(base) = make_uint4(                                     \
                pk(SAp0.x, SAp1.x), pk(SAp0.y, SAp1.y),                       \
                pk(SAp0.z, SAp1.z), pk(SAp0.w, SAp1.w));                      \
            *(uint4*)(base + PAIR_B) = make_uint4(                            \
                pk(SAq0.x, SAq1.x), pk(SAq0.y, SAq1.y),                       \
                pk(SAq0.z, SAq1.z), pk(SAq0.w, SAq1.w));                      \
        }                                                                     \
    } while (0);

    #define FPAIR(BB) {                                                       \
        uint4 A0 = *(const uint4*)((BB) + aof);                               \
        uint4 W0 = *(const uint4*)((BB) + wof);                               \
        uint4 W1 = *(const uint4*)((BB) + wof + 16);                          \
        uint4 W2 = *(const uint4*)((BB) + wof + 32);                          \
        if (mzW0) W0 = make_uint4(0u, 0u, 0u, 0u);                            \
        if (mzW2) W2 = make_uint4(0u, 0u, 0u, 0u);                            \
        unsigned a[4]  = {A0.x, A0.y, A0.z, A0.w};                            \
        unsigned w[12] = {W0.x, W0.y, W0.z, W0.w, W1.x, W1.y, W1.z, W1.w,     \
                          W2.x, W2.y, W2.z, W2.w};                            \
        _Pragma("unroll")                                                     \
        for (int dx = 0; dx < ND; ++dx) {                                     \
            _Pragma("unroll")                                                 \
            for (int j = 0; j < TX; ++j)                                      \
                acc[dx][j] = dot2acc(a[j], w[dx + j], acc[dx][j]);            \
        }                                                                     \
    }

    #define COMPUTE(BUFI)                                                     \
    if (isComp) {                                                             \
        const char* bb = (const char*)lds + (BUFI) * BUF_B;                   \
        FPAIR(bb)                                                             \
        FPAIR(bb + PAIR_B)                                                    \
    }

    // body kc: CVTW chunk kc+1 into buf (kc+1)%3 (regs loaded last body);
    // LOADS chunk kc+2; COMPUTE kc from buf kc%3 (written one barrier ago);
    // ONE __syncthreads. Buf (kc+1)%3 held chunk kc-2, read 2 barriers ago.
    #define BODY(BUFC, BUFW, DOW, DOL)                                        \
        if (DOW) { CVTW(BUFW) }                                               \
        if (DOL) { LOADS }                                                    \
        COMPUTE(BUFC)                                                         \
        __syncthreads();

    // ---- prologue: c0 -> buf0; c1 raw in regs
    LOADS              // c0
    CVTW(0)
    LOADS              // c1
    __syncthreads();

    // ---- main loop: kc = 0..59
    #pragma unroll 1
    for (int g = 0; g < 20; ++g) {
        BODY(0, 1, true, true)
        BODY(1, 2, true, true)
        BODY(2, 0, true, true)
    }
    // ---- tail: kc = 60..63
    BODY(0, 1, true, true)    // writes c61, loads c62
    BODY(1, 2, true, true)    // writes c62, loads c63
    BODY(2, 0, true, false)   // writes c63
    BODY(0, 1, false, false)  // kc=63

    #undef BODY
    #undef COMPUTE
    #undef FPAIR
    #undef CVTW
    #undef LOADS

    // ---- epilogue: OOB-dy rows output zeros via masked scale
    if (isComp) {
        const float m = rowOk ? (1.0f / (float)C_) : 0.f;
        float* outp = out + ((size_t)(b * NDISP + dy * ND) * H_ + y) * W_ + x0;
        #pragma unroll
        for (int dx = 0; dx < ND; ++dx) {
            float4 o = make_float4(acc[dx][0] * m, acc[dx][1] * m,
                                   acc[dx][2] * m, acc[dx][3] * m);
            *(float4*)(outp + dx * HW) = o;
        }
    }
}

extern "C" void kernel_launch(void* const* d_in, const int* in_sizes, int n_in,
                              void* d_out, int out_size, void* d_ws, size_t ws_size,
                              hipStream_t stream) {
    const float* in1 = (const float*)d_in[0];
    const float* in2 = (const float*)d_in[1];
    float* out = (float*)d_out;

    const int grid = B_ * H_ * 2;   // 1536 blocks (b, y, half) = 6 per CU
    corr_ck4_kernel<<<grid, NTHR, 0, stream>>>(in1, in2, out);
}